// Round 10
// baseline (2293.697 us; speedup 1.0000x reference)
//
#include <hip/hip_runtime.h>
#include <stdint.h>

#define BETA 0.9f
#define NIN 784
#define KA0 832            // 784 padded to multiple of 64
#define NHID 2048
#define BATCH 128
#define TSTEPS 32
#define MROWS 4096         // 32*128

typedef float f32x4 __attribute__((ext_vector_type(4)));
typedef int   i32x4 __attribute__((ext_vector_type(4)));

// i8 plane scales (powers of 2; decomposition residual <= 2^-28)
#define S1F 0x1p-11f
#define S2F 0x1p-19f
#define S3F 0x1p-27f

// ---------- helpers ----------
__device__ __forceinline__ float nofuse(float x) {  // block fp-contraction
  asm volatile("" : "+v"(x));
  return x;
}

typedef __attribute__((address_space(1))) const unsigned int gas_uint;
typedef __attribute__((address_space(3))) unsigned int las_uint;
__device__ __forceinline__ void gload_lds16(const void* g, void* l) {
  __builtin_amdgcn_global_load_lds((gas_uint*)g, (las_uint*)l, 16, 0, 0);
}

// ---------- ws layout (i8 planes + i8 spikes) ----------
static const size_t SZ_WS0  = (size_t)3 * 2048 * KA0;        // i8
static const size_t SZ_WSH  = (size_t)3 * 2048 * 2048;       // i8
static const size_t SZ_W4T  = (size_t)2048 * 16 * 4;
static const size_t SZ_SPK  = (size_t)MROWS * 2048;          // i8
static const size_t SZ_CUR  = (size_t)MROWS * 2048 * 4;
static const size_t SZ_CUR5 = (size_t)MROWS * 16 * 4;
static const size_t SZ_VST  = (size_t)5 * TSTEPS * 256 * 2 * 4;
static const size_t SZ_CST  = (size_t)6 * TSTEPS * 256 * 4;

static const size_t OFF_WS0  = 0;
static const size_t OFF_WS1  = OFF_WS0 + SZ_WS0;
static const size_t OFF_WS2  = OFF_WS1 + SZ_WSH;
static const size_t OFF_WS3  = OFF_WS2 + SZ_WSH;
static const size_t OFF_W4T  = OFF_WS3 + SZ_WSH;
static const size_t OFF_SPKA = OFF_W4T + SZ_W4T;
static const size_t OFF_SPKB = OFF_SPKA + SZ_SPK;
static const size_t OFF_CUR  = OFF_SPKB + SZ_SPK;
static const size_t OFF_CUR5 = OFF_CUR + SZ_CUR;
static const size_t OFF_VST  = OFF_CUR5 + SZ_CUR5;
static const size_t OFF_CST  = OFF_VST + SZ_VST;
static const size_t OFF_CUR2 = OFF_CST + SZ_CST;             // split-K z=1 partials

// ---------- prep: split fp32 W into 3 exact i8 planes ----------
__global__ void k_wsplit(const float* __restrict__ W, signed char* __restrict__ dst,
                         int nrows, int kvalid, int kpad) {
  int idx = blockIdx.x * blockDim.x + threadIdx.x;
  int kq = kvalid >> 2;
  if (idx >= nrows * kq) return;
  int row = idx / kq, k0 = (idx - row * kq) * 4;
  const float* src = W + (size_t)row * kvalid + k0;
  signed char p1[4], p2[4], p3[4];
#pragma unroll
  for (int e = 0; e < 4; ++e) {
    float f = src[e];
    float q1 = rintf(f * 2048.0f);                 // |q1| <= 74 for |W|<=0.036
    float r1 = f - q1 * S1F;                       // exact
    float q2 = rintf(r1 * 524288.0f);              // 2^19
    q2 = fminf(127.f, fmaxf(-127.f, q2));
    float r2 = r1 - q2 * S2F;                      // exact
    float q3 = rintf(r2 * 134217728.0f);           // 2^27
    q3 = fminf(127.f, fmaxf(-127.f, q3));
    p1[e] = (signed char)(int)q1;
    p2[e] = (signed char)(int)q2;
    p3[e] = (signed char)(int)q3;
  }
  size_t base = (size_t)row * kpad + k0;
  size_t plane = (size_t)nrows * kpad;
  *(char4*)(dst + base)             = make_char4(p1[0], p1[1], p1[2], p1[3]);
  *(char4*)(dst + plane + base)     = make_char4(p2[0], p2[1], p2[2], p2[3]);
  *(char4*)(dst + 2 * plane + base) = make_char4(p3[0], p3[1], p3[2], p3[3]);
}

__global__ void k_w4t(const float* __restrict__ W4, float* __restrict__ w4t) {
  int k = blockIdx.x * blockDim.x + threadIdx.x;
  if (k >= 2048) return;
#pragma unroll
  for (int c = 0; c < 16; ++c)
    w4t[(size_t)k * 16 + c] = (c < 10) ? W4[(size_t)c * 2048 + k] : 0.f;
}

// =====================================================================
// Main GEMM: r6's 3-phase counted-vmcnt ladder on i8 MFMA 16x16x64.
// BM=256 BN=128 BK=64(cols), 256 thr, 4 waves (2m x 2n), per-wave 128x64.
// LDS: per buf A 16KB + 3 x B 8KB = 40KB; dbuf 80KB -> 2 blocks/CU.
// Rows are 64B (4 x 16B slots) -> byte-identical swizzle/addressing to
// the r6 bf16 kernel (measured 0 bank conflicts). NT halves (K=64/step).
// Per phase: 32 independent K=64 MFMA (C=0), each folded into the fp32
// accumulator in the MFMA shadow: accf += S_plane * (float)step[e].
// i32 dot is exact (<= 64*127); fold noise ~1e-7, same class as fp32.
// =====================================================================
__global__ __launch_bounds__(256, 2) void k_gemm3p(
    const signed char* __restrict__ A,   // [M][Ka] spikes 0/1
    const signed char* __restrict__ B,   // [3][N][Ka] weight planes
    float* __restrict__ C0,              // z=0 partials [M][N]
    float* __restrict__ C1,              // z=1 partials [M][N]
    int N, int Ka) {
  __shared__ __align__(16) signed char smem[2][40960]; // per buf: A[0,16384) | B s*8192
  const int tid = threadIdx.x;
  const int lane = tid & 63, wv = tid >> 6;

  // z-locked XCD map: z = xcd&1; xcd-pair owns an 8mt x 8nt quadrant
  const int bid = blockIdx.x;
  const int xcd = bid & 7, lid = bid >> 3;           // lid 0..63
  const int z  = xcd & 1;
  const int xg = xcd >> 1;                           // 0..3 quadrant
  const int mt = (xg >> 1) * 8 + (lid >> 3);         // 0..15
  const int nt = (xg & 1) * 8 + (lid & 7);           // 0..15
  const int m0 = mt * 256, n0 = nt * 128;
  const int tot = Ka >> 6;                           // 64-col steps total
  const int s0h = (tot + 1) >> 1;
  const int NT  = z ? (tot - s0h) : s0h;             // steps this z (uneven ok)
  const int koff0 = z ? (s0h << 6) : 0;

  f32x4 accf[8][4];
#pragma unroll
  for (int i = 0; i < 8; ++i)
#pragma unroll
    for (int j = 0; j < 4; ++j) accf[i][j] = (f32x4){0.f, 0.f, 0.f, 0.f};

  // stage chunks [i0,i1) of K-step kt into buf. chunk map per thread:
  // i=0..3 -> A rows, i=4,5 -> B0, i=6,7 -> B1, i=8,9 -> B2
  auto stage_part = [&](int buf, int kt, int i0, int i1) {
    const int koff = koff0 + kt * 64;
    const signed char* Abase = A + (size_t)m0 * Ka + koff;
    for (int i = i0; i < i1; ++i) {
      int c = i * 256 + tid;
      const signed char* src;
      if (c < 1024) {                        // A: 256 rows x 64 i8
        int row = c >> 2, kb = c & 3;
        int gkb = kb ^ ((row >> 1) & 3);     // source pre-swizzle (rule #21)
        src = Abase + (size_t)row * Ka + gkb * 16;
      } else {                               // B planes: 3 x (128 rows x 64 i8)
        int cb = c - 1024;
        int s = cb >> 9, cc = cb & 511;
        int row = cc >> 2, kb = cc & 3;
        int gkb = kb ^ ((row >> 1) & 3);
        src = B + ((size_t)s * N + n0 + row) * Ka + koff + gkb * 16;
      }
      gload_lds16(src, &smem[buf][(i * 256 + wv * 64) * 16]);
    }
  };

  const int wm = wv >> 1, wn = wv & 1;
  const int g = lane >> 4, rr = lane & 15;

  auto readA = [&](int p, i32x4* a) {
#pragma unroll
    for (int mf = 0; mf < 8; ++mf) {
      int row = wm * 128 + mf * 16 + rr;
      int slot = g ^ ((row >> 1) & 3);
      a[mf] = *(const i32x4*)&smem[p][row * 64 + slot * 16];
    }
  };
  auto readB = [&](int p, int s, i32x4* b) {
#pragma unroll
    for (int nf = 0; nf < 4; ++nf) {
      int row = wn * 64 + nf * 16 + rr;
      int slot = g ^ ((row >> 1) & 3);
      b[nf] = *(const i32x4*)&smem[p][16384 + s * 8192 + row * 64 + slot * 16];
    }
  };
  auto cluster = [&](i32x4* a, i32x4* b, float sc) {
    const i32x4 zero = {0, 0, 0, 0};
    __builtin_amdgcn_s_setprio(1);
#pragma unroll
    for (int mf = 0; mf < 8; ++mf)
#pragma unroll
      for (int nf = 0; nf < 4; ++nf) {
        i32x4 st = __builtin_amdgcn_mfma_i32_16x16x64_i8(a[mf], b[nf], zero, 0, 0, 0);
#pragma unroll
        for (int e = 0; e < 4; ++e)
          accf[mf][nf][e] = __fmaf_rn(sc, (float)st[e], accf[mf][nf][e]);
      }
    __builtin_amdgcn_s_setprio(0);
  };

#define PHASE_SYNC(nimm)                                   \
  asm volatile("s_waitcnt vmcnt(" #nimm ")" ::: "memory"); \
  __builtin_amdgcn_sched_barrier(0);                       \
  __builtin_amdgcn_s_barrier();                            \
  __builtin_amdgcn_sched_barrier(0);

  // prologue: stage step 0 fully (outstanding = 10)
  stage_part(0, 0, 0, 10);

  for (int kt = 0; kt < NT - 1; ++kt) {
    const int p = kt & 1;
    i32x4 a[8], b[4];
    // ---- phase 0: A + B0 of kt ready; issue next A ----
    PHASE_SYNC(4)
    stage_part(p ^ 1, kt + 1, 0, 4);
    readA(p, a);
    readB(p, 0, b);
    cluster(a, b, S1F);
    // ---- phase 1: B1 of kt ready; issue next B0,B1 ----
    PHASE_SYNC(6)
    stage_part(p ^ 1, kt + 1, 4, 8);
    readB(p, 1, b);
    cluster(a, b, S2F);
    // ---- phase 2: B2 of kt ready; issue next B2 ----
    PHASE_SYNC(8)
    stage_part(p ^ 1, kt + 1, 8, 10);
    readB(p, 2, b);
    cluster(a, b, S3F);
  }
  { // epilogue step kt = NT-1 (no prefetch; waits 4/2/0)
    const int p = (NT - 1) & 1;
    i32x4 a[8], b[4];
    PHASE_SYNC(4)
    readA(p, a);
    readB(p, 0, b);
    cluster(a, b, S1F);
    PHASE_SYNC(2)
    readB(p, 1, b);
    cluster(a, b, S2F);
    PHASE_SYNC(0)
    readB(p, 2, b);
    cluster(a, b, S3F);
  }
#undef PHASE_SYNC

  float* __restrict__ Cz = z ? C1 : C0;
#pragma unroll
  for (int mf = 0; mf < 8; ++mf)
#pragma unroll
    for (int nf = 0; nf < 4; ++nf) {
      int col = n0 + wn * 64 + nf * 16 + rr;
#pragma unroll
      for (int v = 0; v < 4; ++v) {
        int row = m0 + wm * 128 + mf * 16 + g * 4 + v;  // D: row=(lane>>4)*4+reg, col=lane&15
        Cz[(size_t)row * N + col] = accf[mf][nf][v];
      }
    }
}

// ---------- LIF scans ----------
// layer 0: static input, D=784 (pad 832), grid=128, 128 thr; i8 spikes out
__global__ __launch_bounds__(128) void k_scan0(
    const float* __restrict__ input, signed char* __restrict__ spk0,
    float* __restrict__ vstats, int* __restrict__ cstats) {
  const int b = blockIdx.x, tid = threadIdx.x;
  const int j0 = tid * 8;
  const bool act = (j0 < NIN);
  const int lane = tid & 63, wv = tid >> 6;
  __shared__ float ssum[2][TSTEPS], ssq[2][TSTEPS];
  __shared__ int scnt[2][TSTEPS];
  float iv[8];
  if (act) {
    const float* ip = input + (size_t)b * NIN + j0;
    float4 c0 = *(const float4*)ip, c1 = *(const float4*)(ip + 4);
    iv[0]=c0.x; iv[1]=c0.y; iv[2]=c0.z; iv[3]=c0.w;
    iv[4]=c1.x; iv[5]=c1.y; iv[6]=c1.z; iv[7]=c1.w;
  } else {
#pragma unroll
    for (int e = 0; e < 8; ++e) iv[e] = 0.f;
  }
  float mem[8] = {0,0,0,0,0,0,0,0};
  for (int t = 0; t < TSTEPS; ++t) {
    float sum = 0.f, sq = 0.f; int cnt = 0;
    unsigned long long pk = 0;
#pragma unroll
    for (int e = 0; e < 8; ++e) {
      float reset = mem[e] > 1.0f ? 1.0f : 0.0f;
      float t1 = nofuse(BETA * mem[e]);
      float t2 = nofuse(t1 + iv[e]);
      float mn = t2 - reset;
      mem[e] = mn;
      int s = mn > 1.0f;
      pk |= (unsigned long long)(s ? 1u : 0u) << (8 * e);
      sum += mn; sq = __fmaf_rn(mn, mn, sq); cnt += s;
    }
    if (act)
      *(unsigned long long*)(spk0 + (size_t)(t * BATCH + b) * KA0 + j0) = pk;
#pragma unroll
    for (int o = 32; o > 0; o >>= 1) {
      sum += __shfl_down(sum, o, 64);
      sq  += __shfl_down(sq, o, 64);
      cnt += __shfl_down(cnt, o, 64);
    }
    if (lane == 0) { ssum[wv][t] = sum; ssq[wv][t] = sq; scnt[wv][t] = cnt; }
  }
  __syncthreads();
  if (tid < TSTEPS) {
    int t = tid;
    float s = ssum[0][t] + ssum[1][t];
    float q = ssq[0][t] + ssq[1][t];
    int c = scnt[0][t] + scnt[1][t];
    vstats[((size_t)(0 * TSTEPS + t) * 256 + b) * 2 + 0] = s;
    vstats[((size_t)(0 * TSTEPS + t) * 256 + b) * 2 + 1] = q;
    cstats[(0 * TSTEPS + t) * 256 + b] = c;
  }
}

// layers 1..4: cur = cur0 + cur1 + bias -> LIF -> spk i8
__global__ __launch_bounds__(128) void k_scan(
    const float* __restrict__ cur0, const float* __restrict__ cur1,
    const float* __restrict__ bias,
    signed char* __restrict__ spk, float* __restrict__ vstats,
    int* __restrict__ cstats, int layer) {
  const int blk = blockIdx.x;
  const int b = blk >> 1, half = blk & 1;
  const int tid = threadIdx.x;
  const int j0 = half * 1024 + tid * 8;
  const int lane = tid & 63, wv = tid >> 6;
  __shared__ float ssum[2][TSTEPS], ssq[2][TSTEPS];
  __shared__ int scnt[2][TSTEPS];
  float bs[8];
  {
    const float* bp = bias + j0;
    float4 c0 = *(const float4*)bp, c1 = *(const float4*)(bp + 4);
    bs[0]=c0.x; bs[1]=c0.y; bs[2]=c0.z; bs[3]=c0.w;
    bs[4]=c1.x; bs[5]=c1.y; bs[6]=c1.z; bs[7]=c1.w;
  }
  float mem[8] = {0,0,0,0,0,0,0,0};
  for (int t = 0; t < TSTEPS; ++t) {
    size_t off = (size_t)(t * BATCH + b) * 2048 + j0;
    const float* cp = cur0 + off;
    float4 c0 = *(const float4*)cp, c1 = *(const float4*)(cp + 4);
    float cv[8] = {c0.x, c0.y, c0.z, c0.w, c1.x, c1.y, c1.z, c1.w};
    {
      const float* cq = cur1 + off;
      float4 d0 = *(const float4*)cq, d1 = *(const float4*)(cq + 4);
      float dv[8] = {d0.x, d0.y, d0.z, d0.w, d1.x, d1.y, d1.z, d1.w};
#pragma unroll
      for (int e = 0; e < 8; ++e) cv[e] = nofuse(cv[e] + dv[e]);
    }
    float sum = 0.f, sq = 0.f; int cnt = 0;
    unsigned long long pk = 0;
#pragma unroll
    for (int e = 0; e < 8; ++e) {
      float cc = nofuse(cv[e] + bs[e]);
      float reset = mem[e] > 1.0f ? 1.0f : 0.0f;
      float t1 = nofuse(BETA * mem[e]);
      float t2 = nofuse(t1 + cc);
      float mn = t2 - reset;
      mem[e] = mn;
      int s = mn > 1.0f;
      pk |= (unsigned long long)(s ? 1u : 0u) << (8 * e);
      sum += mn; sq = __fmaf_rn(mn, mn, sq); cnt += s;
    }
    *(unsigned long long*)(spk + (size_t)(t * BATCH + b) * 2048 + j0) = pk;
#pragma unroll
    for (int o = 32; o > 0; o >>= 1) {
      sum += __shfl_down(sum, o, 64);
      sq  += __shfl_down(sq, o, 64);
      cnt += __shfl_down(cnt, o, 64);
    }
    if (lane == 0) { ssum[wv][t] = sum; ssq[wv][t] = sq; scnt[wv][t] = cnt; }
  }
  __syncthreads();
  if (tid < TSTEPS) {
    int t = tid;
    float s = ssum[0][t] + ssum[1][t];
    float q = ssq[0][t] + ssq[1][t];
    int c = scnt[0][t] + scnt[1][t];
    vstats[((size_t)(layer * TSTEPS + t) * 256 + blk) * 2 + 0] = s;
    vstats[((size_t)(layer * TSTEPS + t) * 256 + blk) * 2 + 1] = q;
    cstats[(layer * TSTEPS + t) * 256 + blk] = c;
  }
}

// small final GEMM: cur5[4096x16] = spk4(i8) * W4t (fp32 fma)
__global__ __launch_bounds__(256) void k_gemm4(
    const signed char* __restrict__ spk, const float* __restrict__ w4t,
    float* __restrict__ out) {
  int idx = blockIdx.x * 256 + threadIdx.x;
  int r = idx >> 4, c = idx & 15;
  const signed char* sp = spk + (size_t)r * 2048;
  float acc = 0.f;
  for (int k = 0; k < 2048; k += 4) {
    char4 s4 = *(const char4*)(sp + k);
    acc = __fmaf_rn((float)s4.x, w4t[(size_t)(k + 0) * 16 + c], acc);
    acc = __fmaf_rn((float)s4.y, w4t[(size_t)(k + 1) * 16 + c], acc);
    acc = __fmaf_rn((float)s4.z, w4t[(size_t)(k + 2) * 16 + c], acc);
    acc = __fmaf_rn((float)s4.w, w4t[(size_t)(k + 3) * 16 + c], acc);
  }
  out[(size_t)r * 16 + c] = acc;
}

// layer 5: LIF over cur5, writes spike_out (d_out+5), counts only
__global__ __launch_bounds__(640) void k_scan5(
    const float* __restrict__ cur5, const float* __restrict__ b4,
    float* __restrict__ spike_out, int* __restrict__ cstats) {
  const int tid = threadIdx.x;
  const int idx = blockIdx.x * 640 + tid;
  const int b = idx / 10, j = idx - b * 10;
  const int lane = tid & 63, wv = tid >> 6;
  __shared__ int scnt[10][TSTEPS];
  const float bias = b4[j];
  float mem = 0.f;
  for (int t = 0; t < TSTEPS; ++t) {
    float cc = nofuse(cur5[(size_t)(t * BATCH + b) * 16 + j] + bias);
    float reset = mem > 1.0f ? 1.0f : 0.0f;
    float t1 = nofuse(BETA * mem);
    float t2 = nofuse(t1 + cc);
    float mn = t2 - reset;
    mem = mn;
    int s = mn > 1.0f;
    spike_out[(size_t)t * 1280 + b * 10 + j] = s ? 1.0f : 0.0f;
    int cnt = s;
#pragma unroll
    for (int o = 32; o > 0; o >>= 1) cnt += __shfl_down(cnt, o, 64);
    if (lane == 0) scnt[wv][t] = cnt;
  }
  __syncthreads();
  if (tid < TSTEPS) {
    int t = tid, c = 0;
#pragma unroll
    for (int w = 0; w < 10; ++w) c += scnt[w][t];
    cstats[(5 * TSTEPS + t) * 256 + blockIdx.x] = c;
  }
}

// final reduction
__global__ __launch_bounds__(512) void k_final(
    const float* __restrict__ vstats, const int* __restrict__ cstats,
    float* __restrict__ d_out) {
  __shared__ float varLDS[5][TSTEPS];
  __shared__ float cntLDS[6][TSTEPS];
  int tid = threadIdx.x;
  if (tid < 160) {
    int l = tid / 32, t = tid - l * 32;
    double s = 0.0, q = 0.0;
    for (int b = 0; b < 256; ++b) {
      s += (double)vstats[((size_t)(l * TSTEPS + t) * 256 + b) * 2 + 0];
      q += (double)vstats[((size_t)(l * TSTEPS + t) * 256 + b) * 2 + 1];
    }
    double n = (l == 0) ? (double)(BATCH * NIN) : (double)(BATCH * NHID);
    varLDS[l][t] = (float)((q - s * s / n) / (n - 1.0));
  } else if (tid < 352) {
    int i = (tid - 160) / 32, t = (tid - 160) - i * 32;
    int c = 0;
    for (int b = 0; b < 256; ++b) c += cstats[(i * TSTEPS + t) * 256 + b];
    cntLDS[i][t] = (float)c * (1.0f / 128.0f);
  }
  __syncthreads();
  if (tid < 5) {
    float a = 0.f;
    for (int t = 0; t < TSTEPS; ++t) a = __fadd_rn(a, varLDS[tid][t]);
    d_out[tid] = a / 32.0f;
  } else if (tid >= 8 && tid < 14) {
    int i = tid - 8;
    float a = 0.f;
    for (int t = 0; t < TSTEPS; ++t) a = __fadd_rn(a, cntLDS[i][t]);
    d_out[40965 + i] = a / 4096.0f;
  }
}

// ---------- launch ----------
extern "C" void kernel_launch(void* const* d_in, const int* in_sizes, int n_in,
                              void* d_out, int out_size, void* d_ws, size_t ws_size,
                              hipStream_t stream) {
  const float* input = (const float*)d_in[0];
  const float* W0 = (const float*)d_in[1];
  const float* W1 = (const float*)d_in[2];
  const float* W2 = (const float*)d_in[3];
  const float* W3 = (const float*)d_in[4];
  const float* W4 = (const float*)d_in[5];
  const float* b0 = (const float*)d_in[6];
  const float* b1 = (const float*)d_in[7];
  const float* b2 = (const float*)d_in[8];
  const float* b3 = (const float*)d_in[9];
  const float* b4 = (const float*)d_in[10];

  uint8_t* ws = (uint8_t*)d_ws;
  signed char* ws0  = (signed char*)(ws + OFF_WS0);
  signed char* ws1  = (signed char*)(ws + OFF_WS1);
  signed char* ws2  = (signed char*)(ws + OFF_WS2);
  signed char* ws3  = (signed char*)(ws + OFF_WS3);
  float* w4t        = (float*)(ws + OFF_W4T);
  signed char* spkA = (signed char*)(ws + OFF_SPKA);
  signed char* spkB = (signed char*)(ws + OFF_SPKB);
  float* cur        = (float*)(ws + OFF_CUR);
  float* cur2       = (float*)(ws + OFF_CUR2);
  float* cur5       = (float*)(ws + OFF_CUR5);
  float* vst        = (float*)(ws + OFF_VST);
  int* cst          = (int*)(ws + OFF_CST);
  float* out        = (float*)d_out;

  hipMemsetAsync(ws + OFF_VST, 0, SZ_VST + SZ_CST, stream);
  hipMemsetAsync(ws + OFF_SPKA, 0, (size_t)TSTEPS * BATCH * KA0, stream);
  hipMemsetAsync(ws + OFF_WS0, 0, SZ_WS0, stream);

  {
    int thr = 2048 * (NIN / 4);
    k_wsplit<<<(thr + 255) / 256, 256, 0, stream>>>(W0, ws0, 2048, NIN, KA0);
  }
  {
    int thr = 2048 * (2048 / 4);
    int gb = (thr + 255) / 256;
    k_wsplit<<<gb, 256, 0, stream>>>(W1, ws1, 2048, 2048, 2048);
    k_wsplit<<<gb, 256, 0, stream>>>(W2, ws2, 2048, 2048, 2048);
    k_wsplit<<<gb, 256, 0, stream>>>(W3, ws3, 2048, 2048, 2048);
  }
  k_w4t<<<8, 256, 0, stream>>>(W4, w4t);

  k_scan0<<<BATCH, 128, 0, stream>>>(input, spkA, vst, cst);
  k_gemm3p<<<512, 256, 0, stream>>>(spkA, ws0, cur, cur2, 2048, KA0);
  k_scan<<<256, 128, 0, stream>>>(cur, cur2, b0, spkB, vst, cst, 1);
  k_gemm3p<<<512, 256, 0, stream>>>(spkB, ws1, cur, cur2, 2048, 2048);
  k_scan<<<256, 128, 0, stream>>>(cur, cur2, b1, spkA, vst, cst, 2);
  k_gemm3p<<<512, 256, 0, stream>>>(spkA, ws2, cur, cur2, 2048, 2048);
  k_scan<<<256, 128, 0, stream>>>(cur, cur2, b2, spkB, vst, cst, 3);
  k_gemm3p<<<512, 256, 0, stream>>>(spkB, ws3, cur, cur2, 2048, 2048);
  k_scan<<<256, 128, 0, stream>>>(cur, cur2, b3, spkA, vst, cst, 4);
  k_gemm4<<<256, 256, 0, stream>>>(spkA, w4t, cur5);
  k_scan5<<<2, 640, 0, stream>>>(cur5, b4, out + 5, cst);
  k_final<<<1, 512, 0, stream>>>(vst, cst, out);
}

// Round 12
// 402.035 us; speedup vs baseline: 5.7052x; 5.7052x over previous
//
#include <hip/hip_runtime.h>
#include <stdint.h>

#define BETA 0.9f
#define NIN 784
#define KA0 832            // 784 padded to multiple of 64
#define NHID 2048
#define BATCH 128
#define TSTEPS 32
#define MROWS 4096         // 32*128

typedef float f32x4 __attribute__((ext_vector_type(4)));
typedef int   i32x4 __attribute__((ext_vector_type(4)));

// i8 plane scales (powers of 2; decomposition residual <= 2^-28; verified r10 absmax 1.9e-6)
#define S1F 0x1p-11f
#define S2F 0x1p-19f
#define S3F 0x1p-27f

// ---------- helpers ----------
__device__ __forceinline__ float nofuse(float x) {  // block fp-contraction
  asm volatile("" : "+v"(x));
  return x;
}

typedef __attribute__((address_space(1))) const unsigned int gas_uint;
typedef __attribute__((address_space(3))) unsigned int las_uint;
__device__ __forceinline__ void gload_lds16(const void* g, void* l) {
  __builtin_amdgcn_global_load_lds((gas_uint*)g, (las_uint*)l, 16, 0, 0);
}

// ---------- ws layout (i8 planes + i8 spikes, single C) ----------
static const size_t SZ_WS0  = (size_t)3 * 2048 * KA0;        // i8
static const size_t SZ_WSH  = (size_t)3 * 2048 * 2048;       // i8
static const size_t SZ_W4T  = (size_t)2048 * 16 * 4;
static const size_t SZ_SPK  = (size_t)MROWS * 2048;          // i8
static const size_t SZ_CUR  = (size_t)MROWS * 2048 * 4;
static const size_t SZ_CUR5 = (size_t)MROWS * 16 * 4;
static const size_t SZ_VST  = (size_t)5 * TSTEPS * 256 * 2 * 4;
static const size_t SZ_CST  = (size_t)6 * TSTEPS * 256 * 4;

static const size_t OFF_WS0  = 0;
static const size_t OFF_WS1  = OFF_WS0 + SZ_WS0;
static const size_t OFF_WS2  = OFF_WS1 + SZ_WSH;
static const size_t OFF_WS3  = OFF_WS2 + SZ_WSH;
static const size_t OFF_W4T  = OFF_WS3 + SZ_WSH;
static const size_t OFF_SPKA = OFF_W4T + SZ_W4T;
static const size_t OFF_SPKB = OFF_SPKA + SZ_SPK;
static const size_t OFF_CUR  = OFF_SPKB + SZ_SPK;
static const size_t OFF_CUR5 = OFF_CUR + SZ_CUR;
static const size_t OFF_VST  = OFF_CUR5 + SZ_CUR5;
static const size_t OFF_CST  = OFF_VST + SZ_VST;

// ---------- prep: split fp32 W into 3 exact i8 planes ----------
__global__ void k_wsplit(const float* __restrict__ W, signed char* __restrict__ dst,
                         int nrows, int kvalid, int kpad) {
  int idx = blockIdx.x * blockDim.x + threadIdx.x;
  int kq = kvalid >> 2;
  if (idx >= nrows * kq) return;
  int row = idx / kq, k0 = (idx - row * kq) * 4;
  const float* src = W + (size_t)row * kvalid + k0;
  signed char p1[4], p2[4], p3[4];
#pragma unroll
  for (int e = 0; e < 4; ++e) {
    float f = src[e];
    float q1 = rintf(f * 2048.0f);                 // |q1| <= 74 for |W|<=0.036
    float r1 = f - q1 * S1F;                       // exact
    float q2 = rintf(r1 * 524288.0f);              // 2^19
    q2 = fminf(127.f, fmaxf(-127.f, q2));
    float r2 = r1 - q2 * S2F;                      // exact
    float q3 = rintf(r2 * 134217728.0f);           // 2^27
    q3 = fminf(127.f, fmaxf(-127.f, q3));
    p1[e] = (signed char)(int)q1;
    p2[e] = (signed char)(int)q2;
    p3[e] = (signed char)(int)q3;
  }
  size_t base = (size_t)row * kpad + k0;
  size_t plane = (size_t)nrows * kpad;
  *(char4*)(dst + base)             = make_char4(p1[0], p1[1], p1[2], p1[3]);
  *(char4*)(dst + plane + base)     = make_char4(p2[0], p2[1], p2[2], p2[3]);
  *(char4*)(dst + 2 * plane + base) = make_char4(p3[0], p3[1], p3[2], p3[3]);
}

__global__ void k_w4t(const float* __restrict__ W4, float* __restrict__ w4t) {
  int k = blockIdx.x * blockDim.x + threadIdx.x;
  if (k >= 2048) return;
#pragma unroll
  for (int c = 0; c < 16; ++c)
    w4t[(size_t)k * 16 + c] = (c < 10) ? W4[(size_t)c * 2048 + k] : 0.f;
}

// =====================================================================
// Main GEMM: i8 MFMA 16x16x64, per-plane i32 accumulation through MFMA C
// (exact: <= 2048*127 << 2^31), fp32 fold once at epilogue.
// BM=BN=128, BK=64, 256 thr, 4 waves (2m x 2n), per-wave 64x64.
// LDS: per buf A 8KB + 3xB 8KB = 32KB; dbuf 64KB -> 2 blocks/CU.
// Rows 64B = 4x16B slots; same verified swizzle (0 conflicts, r10).
// grid 512 = 32mt x 16nt, r3's proven XCD map. NO split-K (single C).
// Ladder (issue order A,B0,B1,B2; 8 chunks/thread/step):
//   ph0: vmcnt(4) bar | issue next A(2)     | readA+readB0, 16 MFMA plane0
//   ph1: vmcnt(4) bar | issue next B0,B1(4) | readB1, 16 MFMA plane1
//   ph2: vmcnt(6) bar | issue next B2(2)    | readB2, 16 MFMA plane2
// (epilogue 4/2/0, no issue). Loads never drain to 0 in the loop.
// =====================================================================
__global__ __launch_bounds__(256, 2) void k_gemm3p(
    const signed char* __restrict__ A,   // [M][Ka] spikes 0/1
    const signed char* __restrict__ B,   // [3][N][Ka] weight planes
    float* __restrict__ C,               // [M][N]
    int N, int Ka) {
  __shared__ __align__(16) signed char smem[2][32768]; // per buf: A[0,8192) | B s*8192
  const int tid = threadIdx.x;
  const int lane = tid & 63, wv = tid >> 6;

  // XCD map (r3-proven): 512 blocks -> 8 XCDs x (8mt x 8nt)
  const int bid = blockIdx.x;
  const int xcd = bid & 7, lid = bid >> 3;
  const int by = (xcd >> 1) * 8 + (lid >> 3);        // 0..31
  const int bx = (xcd & 1) * 8 + (lid & 7);          // 0..15
  const int m0 = by * 128, n0 = bx * 128;
  const int NT = Ka >> 6;

  i32x4 acc0[4][4], acc1[4][4], acc2[4][4];
#pragma unroll
  for (int i = 0; i < 4; ++i)
#pragma unroll
    for (int j = 0; j < 4; ++j) {
      acc0[i][j] = (i32x4){0, 0, 0, 0};
      acc1[i][j] = (i32x4){0, 0, 0, 0};
      acc2[i][j] = (i32x4){0, 0, 0, 0};
    }

  // stage chunks [i0,i1) of K-step kt into buf. chunk map per thread:
  // i=0,1 -> A rows; i=2,3 -> B0; i=4,5 -> B1; i=6,7 -> B2
  auto stage_part = [&](int buf, int kt, int i0, int i1) {
    const int koff = kt * 64;
    const signed char* Abase = A + (size_t)m0 * Ka + koff;
    for (int i = i0; i < i1; ++i) {
      int c = i * 256 + tid;
      const signed char* src;
      if (c < 512) {                         // A: 128 rows x 64 i8
        int row = c >> 2, kb = c & 3;
        int gkb = kb ^ ((row >> 1) & 3);     // source pre-swizzle (rule #21)
        src = Abase + (size_t)row * Ka + gkb * 16;
      } else {                               // B planes: 3 x (128 rows x 64 i8)
        int cb = c - 512;
        int s = cb >> 9, cc = cb & 511;
        int row = cc >> 2, kb = cc & 3;
        int gkb = kb ^ ((row >> 1) & 3);
        src = B + ((size_t)s * N + n0 + row) * Ka + koff + gkb * 16;
      }
      gload_lds16(src, &smem[buf][(i * 256 + wv * 64) * 16]);
    }
  };

  const int wm = wv >> 1, wn = wv & 1;
  const int g = lane >> 4, rr = lane & 15;

  auto readA = [&](int p, i32x4* a) {
#pragma unroll
    for (int mf = 0; mf < 4; ++mf) {
      int row = wm * 64 + mf * 16 + rr;
      int slot = g ^ ((row >> 1) & 3);
      a[mf] = *(const i32x4*)&smem[p][row * 64 + slot * 16];
    }
  };
  auto readB = [&](int p, int s, i32x4* b) {
#pragma unroll
    for (int nf = 0; nf < 4; ++nf) {
      int row = wn * 64 + nf * 16 + rr;
      int slot = g ^ ((row >> 1) & 3);
      b[nf] = *(const i32x4*)&smem[p][8192 + s * 8192 + row * 64 + slot * 16];
    }
  };
  auto cluster = [&](i32x4* a, i32x4* b, i32x4 (*acc)[4]) {
    __builtin_amdgcn_s_setprio(1);
#pragma unroll
    for (int mf = 0; mf < 4; ++mf)
#pragma unroll
      for (int nf = 0; nf < 4; ++nf)
        acc[mf][nf] = __builtin_amdgcn_mfma_i32_16x16x64_i8(a[mf], b[nf], acc[mf][nf], 0, 0, 0);
    __builtin_amdgcn_s_setprio(0);
  };

#define PHASE_SYNC(nimm)                                   \
  asm volatile("s_waitcnt vmcnt(" #nimm ")" ::: "memory"); \
  __builtin_amdgcn_sched_barrier(0);                       \
  __builtin_amdgcn_s_barrier();                            \
  __builtin_amdgcn_sched_barrier(0);

  // prologue: stage step 0 fully (outstanding = 8)
  stage_part(0, 0, 0, 8);

  for (int kt = 0; kt < NT - 1; ++kt) {
    const int p = kt & 1;
    i32x4 a[4], b[4];
    // ---- phase 0: A + B0 of kt ready; issue next A ----
    PHASE_SYNC(4)
    stage_part(p ^ 1, kt + 1, 0, 2);
    readA(p, a);
    readB(p, 0, b);
    cluster(a, b, acc0);
    // ---- phase 1: B1 ready (leaves B2 + next A); issue next B0,B1 ----
    PHASE_SYNC(4)
    stage_part(p ^ 1, kt + 1, 2, 6);
    readB(p, 1, b);
    cluster(a, b, acc1);
    // ---- phase 2: B2 ready (leaves next A,B0,B1); issue next B2 ----
    PHASE_SYNC(6)
    stage_part(p ^ 1, kt + 1, 6, 8);
    readB(p, 2, b);
    cluster(a, b, acc2);
  }
  { // epilogue step kt = NT-1 (no prefetch; waits 4/2/0)
    const int p = (NT - 1) & 1;
    i32x4 a[4], b[4];
    PHASE_SYNC(4)
    readA(p, a);
    readB(p, 0, b);
    cluster(a, b, acc0);
    PHASE_SYNC(2)
    readB(p, 1, b);
    cluster(a, b, acc1);
    PHASE_SYNC(0)
    readB(p, 2, b);
    cluster(a, b, acc2);
  }
#undef PHASE_SYNC

  // fold planes once: C = S1*acc0 + S2*acc1 + S3*acc2 (fp32)
#pragma unroll
  for (int mf = 0; mf < 4; ++mf)
#pragma unroll
    for (int nf = 0; nf < 4; ++nf) {
      int col = n0 + wn * 64 + nf * 16 + rr;
#pragma unroll
      for (int v = 0; v < 4; ++v) {
        int row = m0 + wm * 64 + mf * 16 + g * 4 + v;  // D: row=(lane>>4)*4+reg, col=lane&15
        float f = S1F * (float)acc0[mf][nf][v];
        f = __fmaf_rn(S2F, (float)acc1[mf][nf][v], f);
        f = __fmaf_rn(S3F, (float)acc2[mf][nf][v], f);
        C[(size_t)row * N + col] = f;
      }
    }
}

// ---------- LIF scans ----------
// layer 0: static input, D=784 (pad 832), grid=128, 128 thr; i8 spikes out
__global__ __launch_bounds__(128) void k_scan0(
    const float* __restrict__ input, signed char* __restrict__ spk0,
    float* __restrict__ vstats, int* __restrict__ cstats) {
  const int b = blockIdx.x, tid = threadIdx.x;
  const int j0 = tid * 8;
  const bool act = (j0 < NIN);
  const int lane = tid & 63, wv = tid >> 6;
  __shared__ float ssum[2][TSTEPS], ssq[2][TSTEPS];
  __shared__ int scnt[2][TSTEPS];
  float iv[8];
  if (act) {
    const float* ip = input + (size_t)b * NIN + j0;
    float4 c0 = *(const float4*)ip, c1 = *(const float4*)(ip + 4);
    iv[0]=c0.x; iv[1]=c0.y; iv[2]=c0.z; iv[3]=c0.w;
    iv[4]=c1.x; iv[5]=c1.y; iv[6]=c1.z; iv[7]=c1.w;
  } else {
#pragma unroll
    for (int e = 0; e < 8; ++e) iv[e] = 0.f;
  }
  float mem[8] = {0,0,0,0,0,0,0,0};
  for (int t = 0; t < TSTEPS; ++t) {
    float sum = 0.f, sq = 0.f; int cnt = 0;
    unsigned long long pk = 0;
#pragma unroll
    for (int e = 0; e < 8; ++e) {
      float reset = mem[e] > 1.0f ? 1.0f : 0.0f;
      float t1 = nofuse(BETA * mem[e]);
      float t2 = nofuse(t1 + iv[e]);
      float mn = t2 - reset;
      mem[e] = mn;
      int s = mn > 1.0f;
      pk |= (unsigned long long)(s ? 1u : 0u) << (8 * e);
      sum += mn; sq = __fmaf_rn(mn, mn, sq); cnt += s;
    }
    if (act)
      *(unsigned long long*)(spk0 + (size_t)(t * BATCH + b) * KA0 + j0) = pk;
#pragma unroll
    for (int o = 32; o > 0; o >>= 1) {
      sum += __shfl_down(sum, o, 64);
      sq  += __shfl_down(sq, o, 64);
      cnt += __shfl_down(cnt, o, 64);
    }
    if (lane == 0) { ssum[wv][t] = sum; ssq[wv][t] = sq; scnt[wv][t] = cnt; }
  }
  __syncthreads();
  if (tid < TSTEPS) {
    int t = tid;
    float s = ssum[0][t] + ssum[1][t];
    float q = ssq[0][t] + ssq[1][t];
    int c = scnt[0][t] + scnt[1][t];
    vstats[((size_t)(0 * TSTEPS + t) * 256 + b) * 2 + 0] = s;
    vstats[((size_t)(0 * TSTEPS + t) * 256 + b) * 2 + 1] = q;
    cstats[(0 * TSTEPS + t) * 256 + b] = c;
  }
}

// layers 1..4: cur + bias -> LIF -> spk i8
__global__ __launch_bounds__(128) void k_scan(
    const float* __restrict__ cur, const float* __restrict__ bias,
    signed char* __restrict__ spk, float* __restrict__ vstats,
    int* __restrict__ cstats, int layer) {
  const int blk = blockIdx.x;
  const int b = blk >> 1, half = blk & 1;
  const int tid = threadIdx.x;
  const int j0 = half * 1024 + tid * 8;
  const int lane = tid & 63, wv = tid >> 6;
  __shared__ float ssum[2][TSTEPS], ssq[2][TSTEPS];
  __shared__ int scnt[2][TSTEPS];
  float bs[8];
  {
    const float* bp = bias + j0;
    float4 c0 = *(const float4*)bp, c1 = *(const float4*)(bp + 4);
    bs[0]=c0.x; bs[1]=c0.y; bs[2]=c0.z; bs[3]=c0.w;
    bs[4]=c1.x; bs[5]=c1.y; bs[6]=c1.z; bs[7]=c1.w;
  }
  float mem[8] = {0,0,0,0,0,0,0,0};
  for (int t = 0; t < TSTEPS; ++t) {
    size_t off = (size_t)(t * BATCH + b) * 2048 + j0;
    const float* cp = cur + off;
    float4 c0 = *(const float4*)cp, c1 = *(const float4*)(cp + 4);
    float cv[8] = {c0.x, c0.y, c0.z, c0.w, c1.x, c1.y, c1.z, c1.w};
    float sum = 0.f, sq = 0.f; int cnt = 0;
    unsigned long long pk = 0;
#pragma unroll
    for (int e = 0; e < 8; ++e) {
      float cc = nofuse(cv[e] + bs[e]);
      float reset = mem[e] > 1.0f ? 1.0f : 0.0f;
      float t1 = nofuse(BETA * mem[e]);
      float t2 = nofuse(t1 + cc);
      float mn = t2 - reset;
      mem[e] = mn;
      int s = mn > 1.0f;
      pk |= (unsigned long long)(s ? 1u : 0u) << (8 * e);
      sum += mn; sq = __fmaf_rn(mn, mn, sq); cnt += s;
    }
    *(unsigned long long*)(spk + (size_t)(t * BATCH + b) * 2048 + j0) = pk;
#pragma unroll
    for (int o = 32; o > 0; o >>= 1) {
      sum += __shfl_down(sum, o, 64);
      sq  += __shfl_down(sq, o, 64);
      cnt += __shfl_down(cnt, o, 64);
    }
    if (lane == 0) { ssum[wv][t] = sum; ssq[wv][t] = sq; scnt[wv][t] = cnt; }
  }
  __syncthreads();
  if (tid < TSTEPS) {
    int t = tid;
    float s = ssum[0][t] + ssum[1][t];
    float q = ssq[0][t] + ssq[1][t];
    int c = scnt[0][t] + scnt[1][t];
    vstats[((size_t)(layer * TSTEPS + t) * 256 + blk) * 2 + 0] = s;
    vstats[((size_t)(layer * TSTEPS + t) * 256 + blk) * 2 + 1] = q;
    cstats[(layer * TSTEPS + t) * 256 + blk] = c;
  }
}

// small final GEMM: cur5[4096x16] = spk4(i8) * W4t (fp32 fma)
__global__ __launch_bounds__(256) void k_gemm4(
    const signed char* __restrict__ spk, const float* __restrict__ w4t,
    float* __restrict__ out) {
  int idx = blockIdx.x * 256 + threadIdx.x;
  int r = idx >> 4, c = idx & 15;
  const signed char* sp = spk + (size_t)r * 2048;
  float acc = 0.f;
  for (int k = 0; k < 2048; k += 4) {
    char4 s4 = *(const char4*)(sp + k);
    acc = __fmaf_rn((float)s4.x, w4t[(size_t)(k + 0) * 16 + c], acc);
    acc = __fmaf_rn((float)s4.y, w4t[(size_t)(k + 1) * 16 + c], acc);
    acc = __fmaf_rn((float)s4.z, w4t[(size_t)(k + 2) * 16 + c], acc);
    acc = __fmaf_rn((float)s4.w, w4t[(size_t)(k + 3) * 16 + c], acc);
  }
  out[(size_t)r * 16 + c] = acc;
}

// layer 5: LIF over cur5, writes spike_out (d_out+5), counts only
__global__ __launch_bounds__(640) void k_scan5(
    const float* __restrict__ cur5, const float* __restrict__ b4,
    float* __restrict__ spike_out, int* __restrict__ cstats) {
  const int tid = threadIdx.x;
  const int idx = blockIdx.x * 640 + tid;
  const int b = idx / 10, j = idx - b * 10;
  const int lane = tid & 63, wv = tid >> 6;
  __shared__ int scnt[10][TSTEPS];
  const float bias = b4[j];
  float mem = 0.f;
  for (int t = 0; t < TSTEPS; ++t) {
    float cc = nofuse(cur5[(size_t)(t * BATCH + b) * 16 + j] + bias);
    float reset = mem > 1.0f ? 1.0f : 0.0f;
    float t1 = nofuse(BETA * mem);
    float t2 = nofuse(t1 + cc);
    float mn = t2 - reset;
    mem = mn;
    int s = mn > 1.0f;
    spike_out[(size_t)t * 1280 + b * 10 + j] = s ? 1.0f : 0.0f;
    int cnt = s;
#pragma unroll
    for (int o = 32; o > 0; o >>= 1) cnt += __shfl_down(cnt, o, 64);
    if (lane == 0) scnt[wv][t] = cnt;
  }
  __syncthreads();
  if (tid < TSTEPS) {
    int t = tid, c = 0;
#pragma unroll
    for (int w = 0; w < 10; ++w) c += scnt[w][t];
    cstats[(5 * TSTEPS + t) * 256 + blockIdx.x] = c;
  }
}

// final reduction
__global__ __launch_bounds__(512) void k_final(
    const float* __restrict__ vstats, const int* __restrict__ cstats,
    float* __restrict__ d_out) {
  __shared__ float varLDS[5][TSTEPS];
  __shared__ float cntLDS[6][TSTEPS];
  int tid = threadIdx.x;
  if (tid < 160) {
    int l = tid / 32, t = tid - l * 32;
    double s = 0.0, q = 0.0;
    for (int b = 0; b < 256; ++b) {
      s += (double)vstats[((size_t)(l * TSTEPS + t) * 256 + b) * 2 + 0];
      q += (double)vstats[((size_t)(l * TSTEPS + t) * 256 + b) * 2 + 1];
    }
    double n = (l == 0) ? (double)(BATCH * NIN) : (double)(BATCH * NHID);
    varLDS[l][t] = (float)((q - s * s / n) / (n - 1.0));
  } else if (tid < 352) {
    int i = (tid - 160) / 32, t = (tid - 160) - i * 32;
    int c = 0;
    for (int b = 0; b < 256; ++b) c += cstats[(i * TSTEPS + t) * 256 + b];
    cntLDS[i][t] = (float)c * (1.0f / 128.0f);
  }
  __syncthreads();
  if (tid < 5) {
    float a = 0.f;
    for (int t = 0; t < TSTEPS; ++t) a = __fadd_rn(a, varLDS[tid][t]);
    d_out[tid] = a / 32.0f;
  } else if (tid >= 8 && tid < 14) {
    int i = tid - 8;
    float a = 0.f;
    for (int t = 0; t < TSTEPS; ++t) a = __fadd_rn(a, cntLDS[i][t]);
    d_out[40965 + i] = a / 4096.0f;
  }
}

// ---------- launch ----------
extern "C" void kernel_launch(void* const* d_in, const int* in_sizes, int n_in,
                              void* d_out, int out_size, void* d_ws, size_t ws_size,
                              hipStream_t stream) {
  const float* input = (const float*)d_in[0];
  const float* W0 = (const float*)d_in[1];
  const float* W1 = (const float*)d_in[2];
  const float* W2 = (const float*)d_in[3];
  const float* W3 = (const float*)d_in[4];
  const float* W4 = (const float*)d_in[5];
  const float* b0 = (const float*)d_in[6];
  const float* b1 = (const float*)d_in[7];
  const float* b2 = (const float*)d_in[8];
  const float* b3 = (const float*)d_in[9];
  const float* b4 = (const float*)d_in[10];

  uint8_t* ws = (uint8_t*)d_ws;
  signed char* ws0  = (signed char*)(ws + OFF_WS0);
  signed char* ws1  = (signed char*)(ws + OFF_WS1);
  signed char* ws2  = (signed char*)(ws + OFF_WS2);
  signed char* ws3  = (signed char*)(ws + OFF_WS3);
  float* w4t        = (float*)(ws + OFF_W4T);
  signed char* spkA = (signed char*)(ws + OFF_SPKA);
  signed char* spkB = (signed char*)(ws + OFF_SPKB);
  float* cur        = (float*)(ws + OFF_CUR);
  float* cur5       = (float*)(ws + OFF_CUR5);
  float* vst        = (float*)(ws + OFF_VST);
  int* cst          = (int*)(ws + OFF_CST);
  float* out        = (float*)d_out;

  hipMemsetAsync(ws + OFF_VST, 0, SZ_VST + SZ_CST, stream);
  hipMemsetAsync(ws + OFF_SPKA, 0, (size_t)TSTEPS * BATCH * KA0, stream);
  hipMemsetAsync(ws + OFF_WS0, 0, SZ_WS0, stream);

  {
    int thr = 2048 * (NIN / 4);
    k_wsplit<<<(thr + 255) / 256, 256, 0, stream>>>(W0, ws0, 2048, NIN, KA0);
  }
  {
    int thr = 2048 * (2048 / 4);
    int gb = (thr + 255) / 256;
    k_wsplit<<<gb, 256, 0, stream>>>(W1, ws1, 2048, 2048, 2048);
    k_wsplit<<<gb, 256, 0, stream>>>(W2, ws2, 2048, 2048, 2048);
    k_wsplit<<<gb, 256, 0, stream>>>(W3, ws3, 2048, 2048, 2048);
  }
  k_w4t<<<8, 256, 0, stream>>>(W4, w4t);

  k_scan0<<<BATCH, 128, 0, stream>>>(input, spkA, vst, cst);
  k_gemm3p<<<512, 256, 0, stream>>>(spkA, ws0, cur, 2048, KA0);
  k_scan<<<256, 128, 0, stream>>>(cur, b0, spkB, vst, cst, 1);
  k_gemm3p<<<512, 256, 0, stream>>>(spkB, ws1, cur, 2048, 2048);
  k_scan<<<256, 128, 0, stream>>>(cur, b1, spkA, vst, cst, 2);
  k_gemm3p<<<512, 256, 0, stream>>>(spkA, ws2, cur, 2048, 2048);
  k_scan<<<256, 128, 0, stream>>>(cur, b2, spkB, vst, cst, 3);
  k_gemm3p<<<512, 256, 0, stream>>>(spkB, ws3, cur, 2048, 2048);
  k_scan<<<256, 128, 0, stream>>>(cur, b3, spkA, vst, cst, 4);
  k_gemm4<<<256, 256, 0, stream>>>(spkA, w4t, cur5);
  k_scan5<<<2, 640, 0, stream>>>(cur5, b4, out + 5, cst);
  k_final<<<1, 512, 0, stream>>>(vst, cst, out);
}